// Round 3
// baseline (1418.086 us; speedup 1.0000x reference)
//
#include <hip/hip_runtime.h>
#include <hip/hip_bf16.h>
#include <math.h>

#define N_ATOMS 2048
#define E_EDGES 65536
#define B_BATCH 8
#define H_DIM 128
#define G_DIM 50
#define F_DIM 64
#define S_DIM 16
#define MH_DIM 32
#define K_TOP 512
#define L_LAYERS 2

static constexpr float STEP   = 10.0f / 49.0f;          // OFFSET spacing
static constexpr float COEFF  = -12.005f;               // -0.5/STEP^2
static constexpr float PI10   = 0.31415926535897931f;   // pi/CUTOFF
static constexpr float LN2    = 0.69314718055994531f;
static constexpr float LAMBDA = 0.002f;

#define DEV static __device__ __forceinline__

DEV float ssp_f(float x) { return fmaxf(x, 0.f) + log1pf(expf(-fabsf(x))) - LN2; }
DEV float ccut_f(float d) { return 0.5f * (cosf(d * PI10) + 1.f); }
DEV float sigm_f(float x) { return 1.f / (1.f + expf(-x)); }

// ---------------- dtype detect: bf16-interp of fp32 data shows huge/NaN values ----------------
__global__ __launch_bounds__(256) void k_detect(const unsigned short* raw, int n, int* flag) {
    __shared__ int any;
    if (threadIdx.x == 0) any = 0;
    __syncthreads();
    for (int i = threadIdx.x; i < n; i += 256) {
        unsigned int bits = ((unsigned int)raw[i]) << 16;
        float f = __uint_as_float(bits);
        if (!(fabsf(f) <= 1e10f)) any = 1;   // catches NaN and huge => source is fp32
    }
    __syncthreads();
    if (threadIdx.x == 0) flag[0] = any;
}

// ---------------- convert input (fp32 or bf16 storage) -> fp32 ----------------
__global__ __launch_bounds__(256) void k_convert(const void* src, float* dst, int n, const int* flag) {
    int i = blockIdx.x * 256 + threadIdx.x;
    if (i >= n) return;
    if (flag[0]) {
        dst[i] = ((const float*)src)[i];
    } else {
        unsigned int bits = ((unsigned int)((const unsigned short*)src)[i]) << 16;
        dst[i] = __uint_as_float(bits);
    }
}

// ---------------- embedding ----------------
__global__ __launch_bounds__(256) void k_embed(const int* atoms, const float* emb, float* h) {
    int i = blockIdx.x * 256 + threadIdx.x;     // N*H
    int n = i >> 7, c = i & 127;
    h[i] = emb[atoms[n] * H_DIM + c];
}

// ---------------- x = h @ cf1  (M x 128 @ 128 x 64) ----------------
__global__ __launch_bounds__(256) void k_x(const float* __restrict__ h, const float* __restrict__ cf1,
                                           float* __restrict__ x, int M) {
    int wave = threadIdx.x >> 6, lane = threadIdx.x & 63;
    int n = blockIdx.x * 4 + wave;
    if (n >= M) return;
    float acc = 0.f;
    for (int k = 0; k < H_DIM; k++) acc += h[n * H_DIM + k] * cf1[k * F_DIM + lane];
    x[n * F_DIM + lane] = acc;
}

// ---------------- edge filter + scatter into agg (atomic) ----------------
__global__ __launch_bounds__(256) void k_edge(const float* pos, const int* src, const int* dst,
                                              const float* x,
                                              const float* mw1, const float* mb1,
                                              const float* mw2, const float* mb2,
                                              float* agg) {
    __shared__ float mw1s[G_DIM * F_DIM];
    __shared__ float mw2s[F_DIM * F_DIM];
    __shared__ float mb1s[F_DIM], mb2s[F_DIM];
    __shared__ float gb[4][G_DIM], tb[4][F_DIM];
    int t = threadIdx.x, wave = t >> 6, lane = t & 63;
    for (int i = t; i < G_DIM * F_DIM; i += 256) mw1s[i] = mw1[i];
    for (int i = t; i < F_DIM * F_DIM; i += 256) mw2s[i] = mw2[i];
    if (t < F_DIM) { mb1s[t] = mb1[t]; mb2s[t] = mb2[t]; }
    __syncthreads();
    int e = blockIdx.x * 4 + wave;
    int sI = src[e], dI = dst[e];
    float dx = pos[sI * 3 + 0] - pos[dI * 3 + 0];
    float dy = pos[sI * 3 + 1] - pos[dI * 3 + 1];
    float dz = pos[sI * 3 + 2] - pos[dI * 3 + 2];
    float d = sqrtf(dx * dx + dy * dy + dz * dz + 1e-12f);
    if (lane < G_DIM) { float u = d - lane * STEP; gb[wave][lane] = expf(COEFF * u * u); }
    __syncthreads();
    float tv = mb1s[lane];
    for (int g = 0; g < G_DIM; g++) tv += gb[wave][g] * mw1s[g * F_DIM + lane];
    tv = ssp_f(tv);
    tb[wave][lane] = tv;
    __syncthreads();
    float w = mb2s[lane];
    for (int k = 0; k < F_DIM; k++) w += tb[wave][k] * mw2s[k * F_DIM + lane];
    w *= ccut_f(d);
    atomicAdd(&agg[dI * F_DIM + lane], x[sI * F_DIM + lane] * w);
}

// ---------------- out = base + ssp(agg@cf2w + cf2b) @ lw + lb ----------------
__global__ __launch_bounds__(256) void k_update(const float* __restrict__ agg, const float* __restrict__ base,
                                                const float* cf2w, const float* cf2b,
                                                const float* lw, const float* lb,
                                                float* out, int M) {
    __shared__ float tbuf[4][H_DIM];
    int wave = threadIdx.x >> 6, lane = threadIdx.x & 63;
    int n = blockIdx.x * 4 + wave;
    float t0 = cf2b[lane], t1 = cf2b[lane + 64];
    if (n < M) {
        for (int f = 0; f < F_DIM; f++) {
            float a = agg[n * F_DIM + f];
            t0 += a * cf2w[f * H_DIM + lane];
            t1 += a * cf2w[f * H_DIM + lane + 64];
        }
    }
    tbuf[wave][lane] = ssp_f(t0);
    tbuf[wave][lane + 64] = ssp_f(t1);
    __syncthreads();
    if (n < M) {
        float o0 = lb[lane], o1 = lb[lane + 64];
        for (int k = 0; k < H_DIM; k++) {
            float tv = tbuf[wave][k];
            o0 += tv * lw[k * H_DIM + lane];
            o1 += tv * lw[k * H_DIM + lane + 64];
        }
        out[n * H_DIM + lane]      = base[n * H_DIM + lane] + o0;
        out[n * H_DIM + lane + 64] = base[n * H_DIM + lane + 64] + o1;
    }
}

// ---------------- node scores ----------------
__global__ __launch_bounds__(256) void k_scores(const float* h_local,
                                                const float* msw1, const float* msb1,
                                                const float* msw2, const float* msb2,
                                                float* scores) {
    int n = blockIdx.x * 256 + threadIdx.x;
    if (n >= N_ATOMS) return;
    float hs[S_DIM];
    for (int s = 0; s < S_DIM; s++) hs[s] = h_local[n * H_DIM + s];
    float sc = msb2[0];
    for (int j = 0; j < MH_DIM; j++) {
        float v = msb1[j];
        for (int s = 0; s < S_DIM; s++) v += hs[s] * msw1[s * MH_DIM + j];
        sc += fmaxf(v, 0.f) * msw2[j];
    }
    scores[n] = sc;
}

// ---------------- exact rank (ties -> lower index wins, matching top_k) ----------------
__global__ __launch_bounds__(256) void k_rank(const float* scores, int* rank) {
    __shared__ float s[N_ATOMS];
    for (int i = threadIdx.x; i < N_ATOMS; i += 256) s[i] = scores[i];
    __syncthreads();
    int i = blockIdx.x * 256 + threadIdx.x;
    float si = s[i];
    int r = 0;
    for (int j = 0; j < N_ATOMS; j++) {
        float sj = s[j];
        r += (sj > si) || (sj == si && j < i);
    }
    rank[i] = r;
}

// ---------------- selection, prefix, midx, m ----------------
__global__ __launch_bounds__(1024) void k_select(const float* scores, const int* rank,
                                                 int* is_m, int* invg, int* midx, float* m) {
    __shared__ int flag[N_ATOMS];
    __shared__ int bufA[N_ATOMS], bufB[N_ATOMS];
    __shared__ float kth;
    int t = threadIdx.x;
    for (int i = t; i < N_ATOMS; i += 1024) {
        int f = rank[i] < K_TOP;
        flag[i] = f;
        bufA[i] = f;
        if (rank[i] == K_TOP - 1) kth = scores[i];
    }
    __syncthreads();
    int* in = bufA;
    int* out = bufB;
    for (int d = 1; d < N_ATOMS; d <<= 1) {
        for (int i = t; i < N_ATOMS; i += 1024) out[i] = in[i] + (i >= d ? in[i - d] : 0);
        __syncthreads();
        int* tmp = in; in = out; out = tmp;
    }
    float kv = kth;
    for (int i = t; i < N_ATOMS; i += 1024) {
        int f = flag[i];
        int pos = in[i] - f;   // exclusive prefix
        is_m[i] = f;
        invg[i] = f ? pos : 0;
        if (f) midx[pos] = i;
        m[i] = sigm_f(scores[i] - kv + 1e-6f);
    }
}

// ---------------- gather h_m / pos_m ----------------
__global__ __launch_bounds__(256) void k_gather(const int* midx, const float* h_local,
                                                const float* pos, float* h_m, float* pos_m) {
    int i = blockIdx.x * 256 + threadIdx.x;  // K*H
    int k = i >> 7, c = i & 127;
    int n = midx[k];
    h_m[i] = h_local[n * H_DIM + c];
    if (c < 3) pos_m[k * 3 + c] = pos[n * 3 + c];
}

// ---------------- adjacency among selected ----------------
__global__ __launch_bounds__(256) void k_adj(const int* src, const int* dst, const int* is_m,
                                             const int* invg, unsigned char* adj) {
    int e = blockIdx.x * 256 + threadIdx.x;
    int s = src[e], d = dst[e];
    if (is_m[s] && is_m[d]) adj[invg[s] * K_TOP + invg[d]] = 1;
}

// ---------------- q/k projections (S=16) ----------------
__global__ __launch_bounds__(32) void k_qk(const float* h_m, const float* wq,
                                           const float* wk, float* qm, float* km) {
    int r = blockIdx.x, t = threadIdx.x;
    const float* w = (t < 16) ? wq : wk;
    int c = t & 15;
    float acc = 0.f;
    for (int s = 0; s < S_DIM; s++) acc += h_m[r * H_DIM + s] * w[s * S_DIM + c];
    if (t < 16) qm[r * S_DIM + c] = acc; else km[r * S_DIM + c] = acc;
}

// ---------------- attention softmax -> Av mask ----------------
__global__ __launch_bounds__(256) void k_attn(const float* qm, const float* km,
                                              const unsigned char* adj, unsigned char* Av) {
    __shared__ float lrow[K_TOP];
    __shared__ float red[256];
    int i = blockIdx.x, t = threadIdx.x;
    float q[S_DIM];
    for (int s = 0; s < S_DIM; s++) q[s] = qm[i * S_DIM + s];
    for (int j = t; j < K_TOP; j += 256) {
        float acc = 0.f;
        for (int s = 0; s < S_DIM; s++) acc += q[s] * km[j * S_DIM + s];
        lrow[j] = acc * 0.25f;   // / sqrt(16)
    }
    __syncthreads();
    float mx = -1e30f;
    for (int j = t; j < K_TOP; j += 256) mx = fmaxf(mx, lrow[j]);
    red[t] = mx; __syncthreads();
    for (int o = 128; o > 0; o >>= 1) { if (t < o) red[t] = fmaxf(red[t], red[t + o]); __syncthreads(); }
    mx = red[0]; __syncthreads();
    float sum = 0.f;
    for (int j = t; j < K_TOP; j += 256) sum += expf(lrow[j] - mx);
    red[t] = sum; __syncthreads();
    for (int o = 128; o > 0; o >>= 1) { if (t < o) red[t] += red[t + o]; __syncthreads(); }
    float inv_s = 1.f / red[0];
    for (int j = t; j < K_TOP; j += 256) {
        float a = expf(lrow[j] - mx) * inv_s;
        Av[i * K_TOP + j] = (a > LAMBDA) && (!adj[i * K_TOP + j]) && (i != j);
    }
}

// ---------------- pairwise distances ----------------
__global__ __launch_bounds__(256) void k_dmat(const float* pos_m, float* dmat) {
    int idx = blockIdx.x * 256 + threadIdx.x;   // K*K
    int i = idx >> 9, j = idx & (K_TOP - 1);
    float dx = pos_m[i * 3 + 0] - pos_m[j * 3 + 0];
    float dy = pos_m[i * 3 + 1] - pos_m[j * 3 + 1];
    float dz = pos_m[i * 3 + 2] - pos_m[j * 3 + 2];
    dmat[idx] = sqrtf(dx * dx + dy * dy + dz * dz + 1e-12f);
}

// ---------------- hi = h_m@Wi, hj = h_m@Wj ----------------
__global__ __launch_bounds__(256) void k_hij(const float* h_m, const float* aw1,
                                             float* hi, float* hj) {
    int wave = threadIdx.x >> 6, lane = threadIdx.x & 63;
    int idx = blockIdx.x * 4 + wave;            // 0..1023
    int which = idx >> 9;
    int r = idx & (K_TOP - 1);
    const float* W = aw1 + which * H_DIM * H_DIM;
    float o0 = 0.f, o1 = 0.f;
    for (int k = 0; k < H_DIM; k++) {
        float hv = h_m[r * H_DIM + k];
        o0 += hv * W[k * H_DIM + lane];
        o1 += hv * W[k * H_DIM + lane + 64];
    }
    float* out = which ? hj : hi;
    out[r * H_DIM + lane] = o0;
    out[r * H_DIM + lane + 64] = o1;
}

// ---------------- per-row attention score + masked softmax -> decay ----------------
__global__ __launch_bounds__(256) void k_score_decay(const float* hi, const float* hj,
                                                     const float* aw1, const float* ab1,
                                                     const float* aw2, const float* ab2,
                                                     const float* dmat, const unsigned char* Av,
                                                     float* decay) {
    __shared__ float Wd[G_DIM * H_DIM];
    __shared__ float his[H_DIM], ab1s[H_DIM], aw2s[H_DIM];
    __shared__ float srow[K_TOP];
    __shared__ float gb[4][G_DIM];
    __shared__ float red[256];
    int i = blockIdx.x, t = threadIdx.x, wave = t >> 6, lane = t & 63;
    const float* wd = aw1 + 2 * H_DIM * H_DIM;
    for (int idx = t; idx < G_DIM * H_DIM; idx += 256) Wd[idx] = wd[idx];
    if (t < H_DIM) { his[t] = hi[i * H_DIM + t]; ab1s[t] = ab1[t]; aw2s[t] = aw2[t]; }
    __syncthreads();
    float b2 = ab2[0];
    for (int j = wave; j < K_TOP; j += 4) {
        bool act = Av[i * K_TOP + j] != 0;
        float sc = -1e9f;
        if (act) {
            float dd = dmat[i * K_TOP + j];
            if (lane < G_DIM) { float u = dd - lane * STEP; gb[wave][lane] = expf(COEFF * u * u); }
            float v0 = his[lane] + hj[j * H_DIM + lane] + ab1s[lane];
            float v1 = his[lane + 64] + hj[j * H_DIM + lane + 64] + ab1s[lane + 64];
            for (int g = 0; g < G_DIM; g++) {
                float gv = gb[wave][g];
                v0 += gv * Wd[g * H_DIM + lane];
                v1 += gv * Wd[g * H_DIM + lane + 64];
            }
            float p = fmaxf(v0, 0.f) * aw2s[lane] + fmaxf(v1, 0.f) * aw2s[lane + 64];
            for (int o = 1; o < 64; o <<= 1) p += __shfl_xor(p, o);
            sc = p + b2;
        }
        if (lane == 0) srow[j] = sc;
    }
    __syncthreads();
    float mx = -1e30f;
    for (int j = t; j < K_TOP; j += 256) mx = fmaxf(mx, srow[j]);
    red[t] = mx; __syncthreads();
    for (int o = 128; o > 0; o >>= 1) { if (t < o) red[t] = fmaxf(red[t], red[t + o]); __syncthreads(); }
    mx = red[0]; __syncthreads();
    float sum = 0.f;
    for (int j = t; j < K_TOP; j += 256) sum += (srow[j] > -5e8f) ? expf(srow[j] - mx) : 0.f;
    red[t] = sum; __syncthreads();
    for (int o = 128; o > 0; o >>= 1) { if (t < o) red[t] += red[t + o]; __syncthreads(); }
    float s_total = red[0];
    float inv_s = (s_total > 0.f) ? 1.f / s_total : 0.f;
    for (int j = t; j < K_TOP; j += 256)
        decay[i * K_TOP + j] = (srow[j] > -5e8f) ? expf(srow[j] - mx) * inv_s : 0.f;
}

// ---------------- agg_d[j] = sum_i xm[i] * Wv[i,j] (block per j) ----------------
__global__ __launch_bounds__(256) void k_aggd(const float* xm, const float* dmat, const float* decay,
                                              const unsigned char* Av,
                                              const float* mw1, const float* mb1,
                                              const float* mw2, const float* mb2,
                                              float* agg_m) {
    __shared__ float mw1s[G_DIM * F_DIM];
    __shared__ float mw2s[F_DIM * F_DIM];
    __shared__ float mb1s[F_DIM], mb2s[F_DIM];
    __shared__ float gb[4][G_DIM], tb[4][F_DIM];
    __shared__ float accs[4][F_DIM];
    int j = blockIdx.x, t = threadIdx.x, wave = t >> 6, lane = t & 63;
    for (int i = t; i < G_DIM * F_DIM; i += 256) mw1s[i] = mw1[i];
    for (int i = t; i < F_DIM * F_DIM; i += 256) mw2s[i] = mw2[i];
    if (t < F_DIM) { mb1s[t] = mb1[t]; mb2s[t] = mb2[t]; }
    __syncthreads();
    float acc = 0.f;
    for (int i = wave; i < K_TOP; i += 4) {
        if (!Av[i * K_TOP + j]) continue;
        float dd = dmat[i * K_TOP + j];
        float dec = decay[i * K_TOP + j];
        if (lane < G_DIM) { float u = dd - lane * STEP; gb[wave][lane] = expf(COEFF * u * u) * dec; }
        float tv = mb1s[lane];
        for (int g = 0; g < G_DIM; g++) tv += gb[wave][g] * mw1s[g * F_DIM + lane];
        tv = ssp_f(tv);
        tb[wave][lane] = tv;
        float w = mb2s[lane];
        for (int k = 0; k < F_DIM; k++) w += tb[wave][k] * mw2s[k * F_DIM + lane];
        acc += xm[i * F_DIM + lane] * w * ccut_f(dd);
    }
    accs[wave][lane] = acc;
    __syncthreads();
    if (wave == 0)
        agg_m[j * F_DIM + lane] = accs[0][lane] + accs[1][lane] + accs[2][lane] + accs[3][lane];
}

// ---------------- valid-edge filter scatter into agg_m (adds on top of agg_d) ----------------
__global__ __launch_bounds__(256) void k_aggs(const float* pos_m, const int* src, const int* dst,
                                              const int* is_m, const int* invg, const float* xm,
                                              const float* mw1, const float* mb1,
                                              const float* mw2, const float* mb2,
                                              float* agg_m) {
    __shared__ float mw1s[G_DIM * F_DIM];
    __shared__ float mw2s[F_DIM * F_DIM];
    __shared__ float mb1s[F_DIM], mb2s[F_DIM];
    __shared__ float gb[4][G_DIM], tb[4][F_DIM];
    int t = threadIdx.x, wave = t >> 6, lane = t & 63;
    for (int i = t; i < G_DIM * F_DIM; i += 256) mw1s[i] = mw1[i];
    for (int i = t; i < F_DIM * F_DIM; i += 256) mw2s[i] = mw2[i];
    if (t < F_DIM) { mb1s[t] = mb1[t]; mb2s[t] = mb2[t]; }
    __syncthreads();
    int e = blockIdx.x * 4 + wave;
    int s = src[e], dn = dst[e];
    bool valid = is_m[s] && is_m[dn];
    int sm = valid ? invg[s] : 0;
    int dm = valid ? invg[dn] : 0;
    float d = 0.f;
    if (valid) {
        float dx = pos_m[sm * 3 + 0] - pos_m[dm * 3 + 0];
        float dy = pos_m[sm * 3 + 1] - pos_m[dm * 3 + 1];
        float dz = pos_m[sm * 3 + 2] - pos_m[dm * 3 + 2];
        d = sqrtf(dx * dx + dy * dy + dz * dz + 1e-12f);
    }
    if (lane < G_DIM) { float u = d - lane * STEP; gb[wave][lane] = expf(COEFF * u * u); }
    __syncthreads();
    float tv = mb1s[lane];
    for (int g = 0; g < G_DIM; g++) tv += gb[wave][g] * mw1s[g * F_DIM + lane];
    tv = ssp_f(tv);
    tb[wave][lane] = tv;
    __syncthreads();
    float w = mb2s[lane];
    for (int k = 0; k < F_DIM; k++) w += tb[wave][k] * mw2s[k * F_DIM + lane];
    if (valid) atomicAdd(&agg_m[dm * F_DIM + lane], xm[sm * F_DIM + lane] * w * ccut_f(d));
}

// ---------------- blend ----------------
__global__ __launch_bounds__(256) void k_blend(const float* h_local, const float* h_hier,
                                               const int* is_m, const int* invg, const float* m,
                                               float* h_out) {
    int idx = blockIdx.x * 256 + threadIdx.x;   // N*H
    int n = idx >> 7, c = idx & 127;
    float mm = m[n];
    float hh = is_m[n] ? h_hier[invg[n] * H_DIM + c] : 0.f;
    h_out[idx] = (1.f - mm) * h_local[idx] + mm * hh;
}

// ---------------- pool + predict (dual-dtype output) ----------------
__global__ __launch_bounds__(128) void k_pred(const float* h, const int* batch,
                                              const float* w1, const float* b1,
                                              const float* w2, const float* b2,
                                              void* outv, const int* flag) {
    __shared__ float pooled[H_DIM];
    __shared__ float c64[64];
    int b = blockIdx.x, t = threadIdx.x;
    float acc = 0.f;
    for (int n = 0; n < N_ATOMS; n++)
        if (batch[n] == b) acc += h[n * H_DIM + t];
    pooled[t] = acc;
    __syncthreads();
    if (t < 64) {
        float v = b1[t];
        for (int k = 0; k < H_DIM; k++) v += pooled[k] * w1[k * 64 + t];
        c64[t] = v * sigm_f(v);   // silu
    }
    __syncthreads();
    if (t == 0) {
        float o = b2[0];
        for (int k = 0; k < 64; k++) o += c64[k] * w2[k];
        if (flag[0]) ((float*)outv)[b] = o;
        else ((__hip_bfloat16*)outv)[b] = __float2bfloat16(o);
    }
}

extern "C" void kernel_launch(void* const* d_in, const int* in_sizes, int n_in,
                              void* d_out, int out_size, void* d_ws, size_t ws_size,
                              hipStream_t stream) {
    (void)n_in; (void)out_size; (void)ws_size;
    const int* atoms = (const int*)d_in[0];
    const int* src = (const int*)d_in[2];
    const int* dst = (const int*)d_in[3];
    const int* batch = (const int*)d_in[4];

    // -------- workspace carve (fp32) --------
    float* W = (float*)d_ws;
    int* dflag = (int*)W; W += 16;     // dtype flag (aligned pad)

    // fp32-converted copies of all float inputs
    static const int fidx[25] = {1,5,6,7,8,9,10,11,12,13,14,15,16,17,18,19,20,21,22,23,24,25,26,27,28};
    float* fin[29];
    // detect BEFORE converts (uses emb = d_in[5])
    k_detect<<<1, 256, 0, stream>>>((const unsigned short*)d_in[5], in_sizes[5], dflag);
    for (int q = 0; q < 25; q++) {
        int i = fidx[q], n = in_sizes[i];
        fin[i] = W; W += n;
        k_convert<<<(n + 255) / 256, 256, 0, stream>>>(d_in[i], fin[i], n, dflag);
    }

    const float* posf = fin[1];
    const float* embf = fin[5];

    float* h      = W; W += N_ATOMS * H_DIM;
    float* h_loc  = W; W += N_ATOMS * H_DIM;
    float* xbuf   = W; W += N_ATOMS * F_DIM;
    float* aggbuf = W; W += N_ATOMS * F_DIM;
    float* scores = W; W += N_ATOMS;
    float* mbuf   = W; W += N_ATOMS;
    float* h_m    = W; W += K_TOP * H_DIM;
    float* pos_m  = W; W += K_TOP * 3;
    float* xm     = W; W += K_TOP * F_DIM;
    float* qm     = W; W += K_TOP * S_DIM;
    float* km     = W; W += K_TOP * S_DIM;
    float* dmat   = W; W += K_TOP * K_TOP;
    float* decay  = W; W += K_TOP * K_TOP;
    float* hi     = W; W += K_TOP * H_DIM;
    float* hj     = W; W += K_TOP * H_DIM;
    float* agg_m  = W; W += K_TOP * F_DIM;
    float* h_hier = W; W += K_TOP * H_DIM;
    int* rankb  = (int*)W; W += N_ATOMS;
    int* is_m   = (int*)W; W += N_ATOMS;
    int* invg   = (int*)W; W += N_ATOMS;
    int* midx   = (int*)W; W += K_TOP;
    unsigned char* adj = (unsigned char*)W; W += (K_TOP * K_TOP) / 4;
    unsigned char* Av  = (unsigned char*)W; W += (K_TOP * K_TOP) / 4;

    k_embed<<<(N_ATOMS * H_DIM) / 256, 256, 0, stream>>>(atoms, embf, h);

    for (int l = 0; l < L_LAYERS; l++) {
        const float* mw1 = fin[6]  + l * G_DIM * F_DIM;
        const float* mb1 = fin[7]  + l * F_DIM;
        const float* mw2 = fin[8]  + l * F_DIM * F_DIM;
        const float* mb2 = fin[9]  + l * F_DIM;
        const float* cf1 = fin[10] + l * H_DIM * F_DIM;
        const float* cf2w = fin[11] + l * F_DIM * H_DIM;
        const float* cf2b = fin[12] + l * H_DIM;
        const float* lw  = fin[13] + l * H_DIM * H_DIM;
        const float* lb  = fin[14] + l * H_DIM;
        const float* aw1 = fin[15] + l * (2 * H_DIM + G_DIM) * H_DIM;
        const float* ab1 = fin[16] + l * H_DIM;
        const float* aw2 = fin[17] + l * H_DIM;
        const float* ab2 = fin[18] + l;
        const float* msw1 = fin[19] + l * S_DIM * MH_DIM;
        const float* msb1 = fin[20] + l * MH_DIM;
        const float* msw2 = fin[21] + l * MH_DIM;
        const float* msb2 = fin[22] + l;
        const float* wq  = fin[23] + l * S_DIM * S_DIM;
        const float* wk  = fin[24] + l * S_DIM * S_DIM;

        k_x<<<N_ATOMS / 4, 256, 0, stream>>>(h, cf1, xbuf, N_ATOMS);
        (void)hipMemsetAsync(aggbuf, 0, N_ATOMS * F_DIM * sizeof(float), stream);
        k_edge<<<E_EDGES / 4, 256, 0, stream>>>(posf, src, dst, xbuf, mw1, mb1, mw2, mb2, aggbuf);
        k_update<<<N_ATOMS / 4, 256, 0, stream>>>(aggbuf, h, cf2w, cf2b, lw, lb, h_loc, N_ATOMS);
        k_scores<<<N_ATOMS / 256, 256, 0, stream>>>(h_loc, msw1, msb1, msw2, msb2, scores);
        k_rank<<<N_ATOMS / 256, 256, 0, stream>>>(scores, rankb);
        k_select<<<1, 1024, 0, stream>>>(scores, rankb, is_m, invg, midx, mbuf);
        k_gather<<<(K_TOP * H_DIM) / 256, 256, 0, stream>>>(midx, h_loc, posf, h_m, pos_m);
        k_x<<<K_TOP / 4, 256, 0, stream>>>(h_m, cf1, xm, K_TOP);
        (void)hipMemsetAsync(adj, 0, K_TOP * K_TOP, stream);
        k_adj<<<E_EDGES / 256, 256, 0, stream>>>(src, dst, is_m, invg, adj);
        k_qk<<<K_TOP, 32, 0, stream>>>(h_m, wq, wk, qm, km);
        k_attn<<<K_TOP, 256, 0, stream>>>(qm, km, adj, Av);
        k_dmat<<<(K_TOP * K_TOP) / 256, 256, 0, stream>>>(pos_m, dmat);
        k_hij<<<(2 * K_TOP) / 4, 256, 0, stream>>>(h_m, aw1, hi, hj);
        k_score_decay<<<K_TOP, 256, 0, stream>>>(hi, hj, aw1, ab1, aw2, ab2, dmat, Av, decay);
        k_aggd<<<K_TOP, 256, 0, stream>>>(xm, dmat, decay, Av, mw1, mb1, mw2, mb2, agg_m);
        k_aggs<<<E_EDGES / 4, 256, 0, stream>>>(pos_m, src, dst, is_m, invg, xm,
                                                mw1, mb1, mw2, mb2, agg_m);
        k_update<<<K_TOP / 4, 256, 0, stream>>>(agg_m, h_m, cf2w, cf2b, lw, lb, h_hier, K_TOP);
        k_blend<<<(N_ATOMS * H_DIM) / 256, 256, 0, stream>>>(h_loc, h_hier, is_m, invg, mbuf, h);
    }

    k_pred<<<B_BATCH, 128, 0, stream>>>(h, batch, fin[25], fin[26], fin[27], fin[28], d_out, dflag);
}

// Round 4
// 983.659 us; speedup vs baseline: 1.4416x; 1.4416x over previous
//
#include <hip/hip_runtime.h>
#include <hip/hip_bf16.h>
#include <math.h>

#define N_ATOMS 2048
#define E_EDGES 65536
#define B_BATCH 8
#define H_DIM 128
#define G_DIM 50
#define F_DIM 64
#define S_DIM 16
#define MH_DIM 32
#define K_TOP 512
#define L_LAYERS 2
#define EPB 64          // edges per block in k_edge/k_aggs (16 per wave)

static constexpr float STEP   = 10.0f / 49.0f;          // OFFSET spacing
static constexpr float COEFF  = -12.005f;               // -0.5/STEP^2
static constexpr float PI10   = 0.31415926535897931f;   // pi/CUTOFF
static constexpr float LN2    = 0.69314718055994531f;
static constexpr float LAMBDA = 0.002f;

#define DEV static __device__ __forceinline__

DEV float ssp_f(float x) { return fmaxf(x, 0.f) + log1pf(expf(-fabsf(x))) - LN2; }
DEV float ccut_f(float d) { return 0.5f * (cosf(d * PI10) + 1.f); }
DEV float sigm_f(float x) { return 1.f / (1.f + expf(-x)); }

// ---------------- dtype detect: bf16-interp of fp32 data shows huge/NaN values ----------------
__global__ __launch_bounds__(256) void k_detect(const unsigned short* raw, int n, int* flag) {
    __shared__ int any;
    if (threadIdx.x == 0) any = 0;
    __syncthreads();
    for (int i = threadIdx.x; i < n; i += 256) {
        unsigned int bits = ((unsigned int)raw[i]) << 16;
        float f = __uint_as_float(bits);
        if (!(fabsf(f) <= 1e10f)) any = 1;   // catches NaN and huge => source is fp32
    }
    __syncthreads();
    if (threadIdx.x == 0) flag[0] = any;
}

// ---------------- fused convert of all float inputs -> fp32 workspace ----------------
struct ConvArgs {
    const void* p[25];
    int off[26];     // prefix offsets into dst; off[25] = total
};

__global__ __launch_bounds__(256) void k_convert_all(ConvArgs a, float* dst, const int* flag) {
    int i = blockIdx.x * 256 + threadIdx.x;
    int total = a.off[25];
    if (i >= total) return;
    int seg = 0;
    while (i >= a.off[seg + 1]) seg++;
    int k = i - a.off[seg];
    if (flag[0]) {
        dst[i] = ((const float*)a.p[seg])[k];
    } else {
        unsigned int bits = ((unsigned int)((const unsigned short*)a.p[seg])[k]) << 16;
        dst[i] = __uint_as_float(bits);
    }
}

// ---------------- embedding ----------------
__global__ __launch_bounds__(256) void k_embed(const int* atoms, const float* emb, float* h) {
    int i = blockIdx.x * 256 + threadIdx.x;     // N*H
    int n = i >> 7, c = i & 127;
    h[i] = emb[atoms[n] * H_DIM + c];
}

// ---------------- x = h @ cf1  (M x 128 @ 128 x 64) ----------------
__global__ __launch_bounds__(256) void k_x(const float* __restrict__ h, const float* __restrict__ cf1,
                                           float* __restrict__ x, int M) {
    int wave = threadIdx.x >> 6, lane = threadIdx.x & 63;
    int n = blockIdx.x * 4 + wave;
    if (n >= M) return;
    float acc = 0.f;
    for (int k = 0; k < H_DIM; k++) acc += h[n * H_DIM + k] * cf1[k * F_DIM + lane];
    x[n * F_DIM + lane] = acc;
}

// ---------------- edge filter + scatter into agg (atomic), EPB edges per block ----------------
__global__ __launch_bounds__(256) void k_edge(const float* pos, const int* src, const int* dst,
                                              const float* x,
                                              const float* mw1, const float* mb1,
                                              const float* mw2, const float* mb2,
                                              float* agg) {
    __shared__ float mw1s[G_DIM * F_DIM];
    __shared__ float mw2s[F_DIM * F_DIM];
    __shared__ float mb1s[F_DIM], mb2s[F_DIM];
    __shared__ float gb[4][G_DIM], tb[4][F_DIM];
    int t = threadIdx.x, wave = t >> 6, lane = t & 63;
    for (int i = t; i < G_DIM * F_DIM; i += 256) mw1s[i] = mw1[i];
    for (int i = t; i < F_DIM * F_DIM; i += 256) mw2s[i] = mw2[i];
    if (t < F_DIM) { mb1s[t] = mb1[t]; mb2s[t] = mb2[t]; }
    __syncthreads();
    int e0 = blockIdx.x * EPB + wave * (EPB / 4);
    for (int ee = 0; ee < EPB / 4; ee++) {
        int e = e0 + ee;
        int sI = src[e], dI = dst[e];
        float dx = pos[sI * 3 + 0] - pos[dI * 3 + 0];
        float dy = pos[sI * 3 + 1] - pos[dI * 3 + 1];
        float dz = pos[sI * 3 + 2] - pos[dI * 3 + 2];
        float d = sqrtf(dx * dx + dy * dy + dz * dz + 1e-12f);
        if (lane < G_DIM) { float u = d - lane * STEP; gb[wave][lane] = expf(COEFF * u * u); }
        // wave-lockstep: per-wave LDS buffers need no barrier
        float tv = mb1s[lane];
        for (int g = 0; g < G_DIM; g++) tv += gb[wave][g] * mw1s[g * F_DIM + lane];
        tv = ssp_f(tv);
        tb[wave][lane] = tv;
        float w = mb2s[lane];
        for (int k = 0; k < F_DIM; k++) w += tb[wave][k] * mw2s[k * F_DIM + lane];
        w *= ccut_f(d);
        atomicAdd(&agg[dI * F_DIM + lane], x[sI * F_DIM + lane] * w);
    }
}

// ---------------- out = base + ssp(agg@cf2w + cf2b) @ lw + lb ----------------
__global__ __launch_bounds__(256) void k_update(const float* __restrict__ agg, const float* __restrict__ base,
                                                const float* cf2w, const float* cf2b,
                                                const float* lw, const float* lb,
                                                float* out, int M) {
    __shared__ float tbuf[4][H_DIM];
    int wave = threadIdx.x >> 6, lane = threadIdx.x & 63;
    int n = blockIdx.x * 4 + wave;
    float t0 = cf2b[lane], t1 = cf2b[lane + 64];
    if (n < M) {
        for (int f = 0; f < F_DIM; f++) {
            float a = agg[n * F_DIM + f];
            t0 += a * cf2w[f * H_DIM + lane];
            t1 += a * cf2w[f * H_DIM + lane + 64];
        }
    }
    tbuf[wave][lane] = ssp_f(t0);
    tbuf[wave][lane + 64] = ssp_f(t1);
    __syncthreads();
    if (n < M) {
        float o0 = lb[lane], o1 = lb[lane + 64];
        for (int k = 0; k < H_DIM; k++) {
            float tv = tbuf[wave][k];
            o0 += tv * lw[k * H_DIM + lane];
            o1 += tv * lw[k * H_DIM + lane + 64];
        }
        out[n * H_DIM + lane]      = base[n * H_DIM + lane] + o0;
        out[n * H_DIM + lane + 64] = base[n * H_DIM + lane + 64] + o1;
    }
}

// ---------------- node scores ----------------
__global__ __launch_bounds__(256) void k_scores(const float* h_local,
                                                const float* msw1, const float* msb1,
                                                const float* msw2, const float* msb2,
                                                float* scores) {
    int n = blockIdx.x * 256 + threadIdx.x;
    if (n >= N_ATOMS) return;
    float hs[S_DIM];
    for (int s = 0; s < S_DIM; s++) hs[s] = h_local[n * H_DIM + s];
    float sc = msb2[0];
    for (int j = 0; j < MH_DIM; j++) {
        float v = msb1[j];
        for (int s = 0; s < S_DIM; s++) v += hs[s] * msw1[s * MH_DIM + j];
        sc += fmaxf(v, 0.f) * msw2[j];
    }
    scores[n] = sc;
}

// ---------------- exact rank (ties -> lower index wins, matching top_k) ----------------
__global__ __launch_bounds__(256) void k_rank(const float* scores, int* rank) {
    __shared__ float s[N_ATOMS];
    for (int i = threadIdx.x; i < N_ATOMS; i += 256) s[i] = scores[i];
    __syncthreads();
    int i = blockIdx.x * 256 + threadIdx.x;
    float si = s[i];
    int r = 0;
    for (int j = 0; j < N_ATOMS; j++) {
        float sj = s[j];
        r += (sj > si) || (sj == si && j < i);
    }
    rank[i] = r;
}

// ---------------- selection, prefix, midx, m ----------------
__global__ __launch_bounds__(1024) void k_select(const float* scores, const int* rank,
                                                 int* is_m, int* invg, int* midx, float* m) {
    __shared__ int flag[N_ATOMS];
    __shared__ int bufA[N_ATOMS], bufB[N_ATOMS];
    __shared__ float kth;
    int t = threadIdx.x;
    for (int i = t; i < N_ATOMS; i += 1024) {
        int f = rank[i] < K_TOP;
        flag[i] = f;
        bufA[i] = f;
        if (rank[i] == K_TOP - 1) kth = scores[i];
    }
    __syncthreads();
    int* in = bufA;
    int* out = bufB;
    for (int d = 1; d < N_ATOMS; d <<= 1) {
        for (int i = t; i < N_ATOMS; i += 1024) out[i] = in[i] + (i >= d ? in[i - d] : 0);
        __syncthreads();
        int* tmp = in; in = out; out = tmp;
    }
    float kv = kth;
    for (int i = t; i < N_ATOMS; i += 1024) {
        int f = flag[i];
        int pos = in[i] - f;   // exclusive prefix
        is_m[i] = f;
        invg[i] = f ? pos : 0;
        if (f) midx[pos] = i;
        m[i] = sigm_f(scores[i] - kv + 1e-6f);
    }
}

// ---------------- gather h_m / pos_m ----------------
__global__ __launch_bounds__(256) void k_gather(const int* midx, const float* h_local,
                                                const float* pos, float* h_m, float* pos_m) {
    int i = blockIdx.x * 256 + threadIdx.x;  // K*H
    int k = i >> 7, c = i & 127;
    int n = midx[k];
    h_m[i] = h_local[n * H_DIM + c];
    if (c < 3) pos_m[k * 3 + c] = pos[n * 3 + c];
}

// ---------------- adjacency among selected ----------------
__global__ __launch_bounds__(256) void k_adj(const int* src, const int* dst, const int* is_m,
                                             const int* invg, unsigned char* adj) {
    int e = blockIdx.x * 256 + threadIdx.x;
    int s = src[e], d = dst[e];
    if (is_m[s] && is_m[d]) adj[invg[s] * K_TOP + invg[d]] = 1;
}

// ---------------- q/k projections (S=16), 256-thread blocks ----------------
__global__ __launch_bounds__(256) void k_qk(const float* h_m, const float* wq,
                                            const float* wk, float* qm, float* km) {
    int gid = blockIdx.x * 256 + threadIdx.x;   // K*32
    int r = gid >> 5, t = gid & 31;
    const float* w = (t < 16) ? wq : wk;
    int c = t & 15;
    float acc = 0.f;
    for (int s = 0; s < S_DIM; s++) acc += h_m[r * H_DIM + s] * w[s * S_DIM + c];
    if (t < 16) qm[r * S_DIM + c] = acc; else km[r * S_DIM + c] = acc;
}

// ---------------- attention softmax -> Av mask ----------------
__global__ __launch_bounds__(256) void k_attn(const float* qm, const float* km,
                                              const unsigned char* adj, unsigned char* Av) {
    __shared__ float lrow[K_TOP];
    __shared__ float red[256];
    int i = blockIdx.x, t = threadIdx.x;
    float q[S_DIM];
    for (int s = 0; s < S_DIM; s++) q[s] = qm[i * S_DIM + s];
    for (int j = t; j < K_TOP; j += 256) {
        float acc = 0.f;
        for (int s = 0; s < S_DIM; s++) acc += q[s] * km[j * S_DIM + s];
        lrow[j] = acc * 0.25f;   // / sqrt(16)
    }
    __syncthreads();
    float mx = -1e30f;
    for (int j = t; j < K_TOP; j += 256) mx = fmaxf(mx, lrow[j]);
    red[t] = mx; __syncthreads();
    for (int o = 128; o > 0; o >>= 1) { if (t < o) red[t] = fmaxf(red[t], red[t + o]); __syncthreads(); }
    mx = red[0]; __syncthreads();
    float sum = 0.f;
    for (int j = t; j < K_TOP; j += 256) sum += expf(lrow[j] - mx);
    red[t] = sum; __syncthreads();
    for (int o = 128; o > 0; o >>= 1) { if (t < o) red[t] += red[t + o]; __syncthreads(); }
    float inv_s = 1.f / red[0];
    for (int j = t; j < K_TOP; j += 256) {
        float a = expf(lrow[j] - mx) * inv_s;
        Av[i * K_TOP + j] = (a > LAMBDA) && (!adj[i * K_TOP + j]) && (i != j);
    }
}

// ---------------- pairwise distances ----------------
__global__ __launch_bounds__(256) void k_dmat(const float* pos_m, float* dmat) {
    int idx = blockIdx.x * 256 + threadIdx.x;   // K*K
    int i = idx >> 9, j = idx & (K_TOP - 1);
    float dx = pos_m[i * 3 + 0] - pos_m[j * 3 + 0];
    float dy = pos_m[i * 3 + 1] - pos_m[j * 3 + 1];
    float dz = pos_m[i * 3 + 2] - pos_m[j * 3 + 2];
    dmat[idx] = sqrtf(dx * dx + dy * dy + dz * dz + 1e-12f);
}

// ---------------- hi = h_m@Wi, hj = h_m@Wj ----------------
__global__ __launch_bounds__(256) void k_hij(const float* h_m, const float* aw1,
                                             float* hi, float* hj) {
    int wave = threadIdx.x >> 6, lane = threadIdx.x & 63;
    int idx = blockIdx.x * 4 + wave;            // 0..1023
    int which = idx >> 9;
    int r = idx & (K_TOP - 1);
    const float* W = aw1 + which * H_DIM * H_DIM;
    float o0 = 0.f, o1 = 0.f;
    for (int k = 0; k < H_DIM; k++) {
        float hv = h_m[r * H_DIM + k];
        o0 += hv * W[k * H_DIM + lane];
        o1 += hv * W[k * H_DIM + lane + 64];
    }
    float* out = which ? hj : hi;
    out[r * H_DIM + lane] = o0;
    out[r * H_DIM + lane + 64] = o1;
}

// ---------------- per-row attention score + masked softmax -> decay ----------------
__global__ __launch_bounds__(256) void k_score_decay(const float* hi, const float* hj,
                                                     const float* aw1, const float* ab1,
                                                     const float* aw2, const float* ab2,
                                                     const float* dmat, const unsigned char* Av,
                                                     float* decay) {
    __shared__ float Wd[G_DIM * H_DIM];
    __shared__ float his[H_DIM], ab1s[H_DIM], aw2s[H_DIM];
    __shared__ float srow[K_TOP];
    __shared__ float gb[4][G_DIM];
    __shared__ float red[256];
    int i = blockIdx.x, t = threadIdx.x, wave = t >> 6, lane = t & 63;
    const float* wd = aw1 + 2 * H_DIM * H_DIM;
    for (int idx = t; idx < G_DIM * H_DIM; idx += 256) Wd[idx] = wd[idx];
    if (t < H_DIM) { his[t] = hi[i * H_DIM + t]; ab1s[t] = ab1[t]; aw2s[t] = aw2[t]; }
    __syncthreads();
    float b2 = ab2[0];
    for (int j = wave; j < K_TOP; j += 4) {
        bool act = Av[i * K_TOP + j] != 0;
        float sc = -1e9f;
        if (act) {
            float dd = dmat[i * K_TOP + j];
            if (lane < G_DIM) { float u = dd - lane * STEP; gb[wave][lane] = expf(COEFF * u * u); }
            float v0 = his[lane] + hj[j * H_DIM + lane] + ab1s[lane];
            float v1 = his[lane + 64] + hj[j * H_DIM + lane + 64] + ab1s[lane + 64];
            for (int g = 0; g < G_DIM; g++) {
                float gv = gb[wave][g];
                v0 += gv * Wd[g * H_DIM + lane];
                v1 += gv * Wd[g * H_DIM + lane + 64];
            }
            float p = fmaxf(v0, 0.f) * aw2s[lane] + fmaxf(v1, 0.f) * aw2s[lane + 64];
            for (int o = 1; o < 64; o <<= 1) p += __shfl_xor(p, o);
            sc = p + b2;
        }
        if (lane == 0) srow[j] = sc;
    }
    __syncthreads();
    float mx = -1e30f;
    for (int j = t; j < K_TOP; j += 256) mx = fmaxf(mx, srow[j]);
    red[t] = mx; __syncthreads();
    for (int o = 128; o > 0; o >>= 1) { if (t < o) red[t] = fmaxf(red[t], red[t + o]); __syncthreads(); }
    mx = red[0]; __syncthreads();
    float sum = 0.f;
    for (int j = t; j < K_TOP; j += 256) sum += (srow[j] > -5e8f) ? expf(srow[j] - mx) : 0.f;
    red[t] = sum; __syncthreads();
    for (int o = 128; o > 0; o >>= 1) { if (t < o) red[t] += red[t + o]; __syncthreads(); }
    float s_total = red[0];
    float inv_s = (s_total > 0.f) ? 1.f / s_total : 0.f;
    for (int j = t; j < K_TOP; j += 256)
        decay[i * K_TOP + j] = (srow[j] > -5e8f) ? expf(srow[j] - mx) * inv_s : 0.f;
}

// ---------------- agg_d[j] = sum_i xm[i] * Wv[i,j] (block per j) ----------------
__global__ __launch_bounds__(256) void k_aggd(const float* xm, const float* dmat, const float* decay,
                                              const unsigned char* Av,
                                              const float* mw1, const float* mb1,
                                              const float* mw2, const float* mb2,
                                              float* agg_m) {
    __shared__ float mw1s[G_DIM * F_DIM];
    __shared__ float mw2s[F_DIM * F_DIM];
    __shared__ float mb1s[F_DIM], mb2s[F_DIM];
    __shared__ float gb[4][G_DIM], tb[4][F_DIM];
    __shared__ float accs[4][F_DIM];
    int j = blockIdx.x, t = threadIdx.x, wave = t >> 6, lane = t & 63;
    for (int i = t; i < G_DIM * F_DIM; i += 256) mw1s[i] = mw1[i];
    for (int i = t; i < F_DIM * F_DIM; i += 256) mw2s[i] = mw2[i];
    if (t < F_DIM) { mb1s[t] = mb1[t]; mb2s[t] = mb2[t]; }
    __syncthreads();
    float acc = 0.f;
    for (int i = wave; i < K_TOP; i += 4) {
        if (!Av[i * K_TOP + j]) continue;
        float dd = dmat[i * K_TOP + j];
        float dec = decay[i * K_TOP + j];
        if (lane < G_DIM) { float u = dd - lane * STEP; gb[wave][lane] = expf(COEFF * u * u) * dec; }
        float tv = mb1s[lane];
        for (int g = 0; g < G_DIM; g++) tv += gb[wave][g] * mw1s[g * F_DIM + lane];
        tv = ssp_f(tv);
        tb[wave][lane] = tv;
        float w = mb2s[lane];
        for (int k = 0; k < F_DIM; k++) w += tb[wave][k] * mw2s[k * F_DIM + lane];
        acc += xm[i * F_DIM + lane] * w * ccut_f(dd);
    }
    accs[wave][lane] = acc;
    __syncthreads();
    if (wave == 0)
        agg_m[j * F_DIM + lane] = accs[0][lane] + accs[1][lane] + accs[2][lane] + accs[3][lane];
}

// ---------------- valid-edge filter scatter into agg_m, EPB edges per block ----------------
__global__ __launch_bounds__(256) void k_aggs(const float* pos_m, const int* src, const int* dst,
                                              const int* is_m, const int* invg, const float* xm,
                                              const float* mw1, const float* mb1,
                                              const float* mw2, const float* mb2,
                                              float* agg_m) {
    __shared__ float mw1s[G_DIM * F_DIM];
    __shared__ float mw2s[F_DIM * F_DIM];
    __shared__ float mb1s[F_DIM], mb2s[F_DIM];
    __shared__ float gb[4][G_DIM], tb[4][F_DIM];
    int t = threadIdx.x, wave = t >> 6, lane = t & 63;
    for (int i = t; i < G_DIM * F_DIM; i += 256) mw1s[i] = mw1[i];
    for (int i = t; i < F_DIM * F_DIM; i += 256) mw2s[i] = mw2[i];
    if (t < F_DIM) { mb1s[t] = mb1[t]; mb2s[t] = mb2[t]; }
    __syncthreads();
    int e0 = blockIdx.x * EPB + wave * (EPB / 4);
    for (int ee = 0; ee < EPB / 4; ee++) {
        int e = e0 + ee;
        int s = src[e], dn = dst[e];
        bool valid = is_m[s] && is_m[dn];
        if (!valid) continue;
        int sm = invg[s];
        int dm = invg[dn];
        float dx = pos_m[sm * 3 + 0] - pos_m[dm * 3 + 0];
        float dy = pos_m[sm * 3 + 1] - pos_m[dm * 3 + 1];
        float dz = pos_m[sm * 3 + 2] - pos_m[dm * 3 + 2];
        float d = sqrtf(dx * dx + dy * dy + dz * dz + 1e-12f);
        if (lane < G_DIM) { float u = d - lane * STEP; gb[wave][lane] = expf(COEFF * u * u); }
        float tv = mb1s[lane];
        for (int g = 0; g < G_DIM; g++) tv += gb[wave][g] * mw1s[g * F_DIM + lane];
        tv = ssp_f(tv);
        tb[wave][lane] = tv;
        float w = mb2s[lane];
        for (int k = 0; k < F_DIM; k++) w += tb[wave][k] * mw2s[k * F_DIM + lane];
        atomicAdd(&agg_m[dm * F_DIM + lane], xm[sm * F_DIM + lane] * w * ccut_f(d));
    }
}

// ---------------- blend ----------------
__global__ __launch_bounds__(256) void k_blend(const float* h_local, const float* h_hier,
                                               const int* is_m, const int* invg, const float* m,
                                               float* h_out) {
    int idx = blockIdx.x * 256 + threadIdx.x;   // N*H
    int n = idx >> 7, c = idx & 127;
    float mm = m[n];
    float hh = is_m[n] ? h_hier[invg[n] * H_DIM + c] : 0.f;
    h_out[idx] = (1.f - mm) * h_local[idx] + mm * hh;
}

// ---------------- parallel segment-sum pooling ----------------
__global__ __launch_bounds__(256) void k_pool(const float* __restrict__ h, const int* __restrict__ batch,
                                              float* pooled) {
    // grid: N_ATOMS/64 blocks; thread: channel c = t&127, atom-stream a = t>>7
    int c = threadIdx.x & 127, a = threadIdx.x >> 7;
    int n0 = blockIdx.x * 64;
    float acc = 0.f;
    int cur = batch[n0 + a];
    for (int i = a; i < 64; i += 2) {
        int n = n0 + i;
        int b = batch[n];
        if (b != cur) { atomicAdd(&pooled[cur * H_DIM + c], acc); acc = 0.f; cur = b; }
        acc += h[n * H_DIM + c];
    }
    atomicAdd(&pooled[cur * H_DIM + c], acc);
}

// ---------------- predict MLP (dual-dtype output) ----------------
__global__ __launch_bounds__(128) void k_pred2(const float* pooled,
                                               const float* w1, const float* b1,
                                               const float* w2, const float* b2,
                                               void* outv, const int* flag) {
    __shared__ float c64[64];
    int b = blockIdx.x, t = threadIdx.x;
    if (t < 64) {
        float v = b1[t];
        for (int k = 0; k < H_DIM; k++) v += pooled[b * H_DIM + k] * w1[k * 64 + t];
        c64[t] = v * sigm_f(v);   // silu
    }
    __syncthreads();
    if (t == 0) {
        float o = b2[0];
        for (int k = 0; k < 64; k++) o += c64[k] * w2[k];
        if (flag[0]) ((float*)outv)[b] = o;
        else ((__hip_bfloat16*)outv)[b] = __float2bfloat16(o);
    }
}

extern "C" void kernel_launch(void* const* d_in, const int* in_sizes, int n_in,
                              void* d_out, int out_size, void* d_ws, size_t ws_size,
                              hipStream_t stream) {
    (void)n_in; (void)out_size; (void)ws_size;
    const int* atoms = (const int*)d_in[0];
    const int* src = (const int*)d_in[2];
    const int* dst = (const int*)d_in[3];
    const int* batch = (const int*)d_in[4];

    // -------- workspace carve (fp32) --------
    float* W = (float*)d_ws;
    int* dflag = (int*)W; W += 16;     // dtype flag (aligned pad)

    // fp32-converted copies of all float inputs (fused single conversion kernel)
    static const int fidx[25] = {1,5,6,7,8,9,10,11,12,13,14,15,16,17,18,19,20,21,22,23,24,25,26,27,28};
    float* fin[29];
    ConvArgs ca;
    float* convBase = W;
    int off = 0;
    for (int q = 0; q < 25; q++) {
        int i = fidx[q];
        ca.p[q] = d_in[i];
        ca.off[q] = off;
        fin[i] = convBase + off;
        off += in_sizes[i];
    }
    ca.off[25] = off;
    W += off;

    k_detect<<<1, 256, 0, stream>>>((const unsigned short*)d_in[5], in_sizes[5], dflag);
    k_convert_all<<<(off + 255) / 256, 256, 0, stream>>>(ca, convBase, dflag);

    const float* posf = fin[1];
    const float* embf = fin[5];

    float* h      = W; W += N_ATOMS * H_DIM;
    float* h_loc  = W; W += N_ATOMS * H_DIM;
    float* xbuf   = W; W += N_ATOMS * F_DIM;
    float* aggbuf = W; W += N_ATOMS * F_DIM;
    float* scores = W; W += N_ATOMS;
    float* mbuf   = W; W += N_ATOMS;
    float* h_m    = W; W += K_TOP * H_DIM;
    float* pos_m  = W; W += K_TOP * 3;
    float* xm     = W; W += K_TOP * F_DIM;
    float* qm     = W; W += K_TOP * S_DIM;
    float* km     = W; W += K_TOP * S_DIM;
    float* dmat   = W; W += K_TOP * K_TOP;
    float* decay  = W; W += K_TOP * K_TOP;
    float* hi     = W; W += K_TOP * H_DIM;
    float* hj     = W; W += K_TOP * H_DIM;
    float* agg_m  = W; W += K_TOP * F_DIM;
    float* h_hier = W; W += K_TOP * H_DIM;
    float* pooled = W; W += B_BATCH * H_DIM;
    int* rankb  = (int*)W; W += N_ATOMS;
    int* is_m   = (int*)W; W += N_ATOMS;
    int* invg   = (int*)W; W += N_ATOMS;
    int* midx   = (int*)W; W += K_TOP;
    unsigned char* adj = (unsigned char*)W; W += (K_TOP * K_TOP) / 4;
    unsigned char* Av  = (unsigned char*)W; W += (K_TOP * K_TOP) / 4;

    k_embed<<<(N_ATOMS * H_DIM) / 256, 256, 0, stream>>>(atoms, embf, h);

    for (int l = 0; l < L_LAYERS; l++) {
        const float* mw1 = fin[6]  + l * G_DIM * F_DIM;
        const float* mb1 = fin[7]  + l * F_DIM;
        const float* mw2 = fin[8]  + l * F_DIM * F_DIM;
        const float* mb2 = fin[9]  + l * F_DIM;
        const float* cf1 = fin[10] + l * H_DIM * F_DIM;
        const float* cf2w = fin[11] + l * F_DIM * H_DIM;
        const float* cf2b = fin[12] + l * H_DIM;
        const float* lw  = fin[13] + l * H_DIM * H_DIM;
        const float* lb  = fin[14] + l * H_DIM;
        const float* aw1 = fin[15] + l * (2 * H_DIM + G_DIM) * H_DIM;
        const float* ab1 = fin[16] + l * H_DIM;
        const float* aw2 = fin[17] + l * H_DIM;
        const float* ab2 = fin[18] + l;
        const float* msw1 = fin[19] + l * S_DIM * MH_DIM;
        const float* msb1 = fin[20] + l * MH_DIM;
        const float* msw2 = fin[21] + l * MH_DIM;
        const float* msb2 = fin[22] + l;
        const float* wq  = fin[23] + l * S_DIM * S_DIM;
        const float* wk  = fin[24] + l * S_DIM * S_DIM;

        k_x<<<N_ATOMS / 4, 256, 0, stream>>>(h, cf1, xbuf, N_ATOMS);
        (void)hipMemsetAsync(aggbuf, 0, N_ATOMS * F_DIM * sizeof(float), stream);
        k_edge<<<E_EDGES / EPB, 256, 0, stream>>>(posf, src, dst, xbuf, mw1, mb1, mw2, mb2, aggbuf);
        k_update<<<N_ATOMS / 4, 256, 0, stream>>>(aggbuf, h, cf2w, cf2b, lw, lb, h_loc, N_ATOMS);
        k_scores<<<N_ATOMS / 256, 256, 0, stream>>>(h_loc, msw1, msb1, msw2, msb2, scores);
        k_rank<<<N_ATOMS / 256, 256, 0, stream>>>(scores, rankb);
        k_select<<<1, 1024, 0, stream>>>(scores, rankb, is_m, invg, midx, mbuf);
        k_gather<<<(K_TOP * H_DIM) / 256, 256, 0, stream>>>(midx, h_loc, posf, h_m, pos_m);
        k_x<<<K_TOP / 4, 256, 0, stream>>>(h_m, cf1, xm, K_TOP);
        (void)hipMemsetAsync(adj, 0, K_TOP * K_TOP, stream);
        k_adj<<<E_EDGES / 256, 256, 0, stream>>>(src, dst, is_m, invg, adj);
        k_qk<<<(K_TOP * 32) / 256, 256, 0, stream>>>(h_m, wq, wk, qm, km);
        k_attn<<<K_TOP, 256, 0, stream>>>(qm, km, adj, Av);
        k_dmat<<<(K_TOP * K_TOP) / 256, 256, 0, stream>>>(pos_m, dmat);
        k_hij<<<(2 * K_TOP) / 4, 256, 0, stream>>>(h_m, aw1, hi, hj);
        k_score_decay<<<K_TOP, 256, 0, stream>>>(hi, hj, aw1, ab1, aw2, ab2, dmat, Av, decay);
        k_aggd<<<K_TOP, 256, 0, stream>>>(xm, dmat, decay, Av, mw1, mb1, mw2, mb2, agg_m);
        k_aggs<<<E_EDGES / EPB, 256, 0, stream>>>(pos_m, src, dst, is_m, invg, xm,
                                                  mw1, mb1, mw2, mb2, agg_m);
        k_update<<<K_TOP / 4, 256, 0, stream>>>(agg_m, h_m, cf2w, cf2b, lw, lb, h_hier, K_TOP);
        k_blend<<<(N_ATOMS * H_DIM) / 256, 256, 0, stream>>>(h_loc, h_hier, is_m, invg, mbuf, h);
    }

    (void)hipMemsetAsync(pooled, 0, B_BATCH * H_DIM * sizeof(float), stream);
    k_pool<<<N_ATOMS / 64, 256, 0, stream>>>(h, batch, pooled);
    k_pred2<<<B_BATCH, 128, 0, stream>>>(pooled, fin[25], fin[26], fin[27], fin[28], d_out, dflag);
}